// Round 12
// baseline (190.879 us; speedup 1.0000x reference)
//
#include <hip/hip_runtime.h>

#define NROWS 16384
#define DDIM  4096
#define NEXP  64
#define TAU   1e-3f
#define FB    1024        // fused blocks: 16 rows each, 4 waves (K-quarters)
#define RB    2048        // repair worker blocks
#define RBLK  64          // reduce_stage output blocks

typedef __attribute__((ext_vector_type(8))) short bf16x8;
typedef __attribute__((ext_vector_type(4))) float f32x4;

__device__ __forceinline__ ushort f2bf(float f) {   // fp32 -> bf16 RN-even
    uint u = __float_as_uint(f);
    u += 0x7FFFu + ((u >> 16) & 1u);
    return (ushort)(u >> 16);
}
__device__ __forceinline__ float bf2f(ushort h) {
    return __uint_as_float(((uint)h) << 16);
}
__device__ __forceinline__ void cvt8(const float4& a, const float4& b,
                                     bf16x8& H, bf16x8& L) {
    const float v[8] = {a.x, a.y, a.z, a.w, b.x, b.y, b.z, b.w};
    #pragma unroll
    for (int i = 0; i < 8; ++i) {
        const ushort h = f2bf(v[i]);
        H[i] = (short)h;
        L[i] = (short)f2bf(v[i] - bf2f(h));
    }
}
// non-temporal float4 load (keeps the zero-reuse x stream out of L2 so the
// W-fragment table stays L2-resident)
__device__ __forceinline__ float4 ntload4(const float* p) {
    f32x4 v = __builtin_nontemporal_load((const f32x4*)p);
    return make_float4(v[0], v[1], v[2], v[3]);
}

// ---------------- Kernel P: W -> fragment-major bf16 hi/lo (once, 2 MB) ----
// Chunk c (64 k) = wfrag[c*8192 ..). Fragment f=(ks*4+nt)*2+prod at
// [f*512 + lane*8]: W[c*64+ks*32+8*(lane>>4)+j][nt*16+(lane&15)].
// (Layout verified by R8-R11 passing refcheck.)
__global__ __launch_bounds__(256) void wprep(
    const float* __restrict__ Wg, ushort* __restrict__ wfrag)
{
    const int gid  = (int)blockIdx.x * 256 + threadIdx.x;   // 0..32767
    const int lane = gid & 63, frag = gid >> 6;             // frag 0..511
    const int nt = frag & 3, ks = (frag >> 2) & 1, tg = frag >> 3;
    const int k0 = tg * 64 + ks * 32 + (lane >> 4) * 8;
    const int e  = nt * 16 + (lane & 15);
    bf16x8 H, L;
    #pragma unroll
    for (int j = 0; j < 8; ++j) {
        const float v = Wg[(size_t)(k0 + j) * NEXP + e];
        const ushort h = f2bf(v);
        H[j] = (short)h;
        L[j] = (short)f2bf(v - bf2f(h));
    }
    *(bf16x8*)&wfrag[((size_t)frag * 2 + 0) * 512 + lane * 8] = H;
    *(bf16x8*)&wfrag[((size_t)frag * 2 + 1) * 512 + lane * 8] = L;
}

// ---------------- Kernel A: barrier-free per-wave MFMA GEMM + epilogue ----
// 1024 blocks x 256 thr (4 waves). Block = rows rg*16..+15; wave w = K-quarter
// (1024 k, 16 chunks of 64). Per chunk: ALL 16 W-fragment loads issued as one
// batch into registers (one vmcnt wait, not 8 serialized round-trips — R11's
// 6100 cyc/chunk stall), then 24 MFMAs. x via non-temporal loads.
__global__ __launch_bounds__(256, 4) void router_fused(
    const float* __restrict__ x, const ushort* __restrict__ wfrag,
    const float* __restrict__ noise, float* __restrict__ out_gates,
    float* __restrict__ out_idx, float* __restrict__ ws_imp,
    float* __restrict__ ws_load, int* __restrict__ worklist,
    int* __restrict__ counter)
{
    __shared__ float patch[4][16][66];   // per-wave logits patch, 16.9 KB
    __shared__ float red[4][NEXP];       // 1 KB

    const int tid  = threadIdx.x;
    const int lane = tid & 63;
    const int w    = tid >> 6;           // wave = K-quarter 0..3
    const int rg   = blockIdx.x;         // row-group 0..1023
    const int fr   = lane & 15;
    const int q    = lane >> 4;

    const float* xp = x + (size_t)(rg * 16 + fr) * DDIM + w * 1024 + q * 8;
    const ushort* wfbase = wfrag + (size_t)(w * 16) * 8192 + lane * 8;

    f32x4 acc[4];
    #pragma unroll
    for (int nt = 0; nt < 4; ++nt) acc[nt] = (f32x4){0.f, 0.f, 0.f, 0.f};

    // prologue: x chunk 0
    float4 c0a = ntload4(xp);
    float4 c0b = ntload4(xp + 4);
    float4 c1a = ntload4(xp + 32);
    float4 c1b = ntload4(xp + 36);

    for (int t = 0; t < 16; ++t) {
        // batch-issue ALL 16 W-fragment loads for this chunk (independent,
        // single base + immediate offsets -> one vmcnt group)
        const ushort* wt = wfbase + (size_t)t * 8192;
        bf16x8 wb[16];
        #pragma unroll
        for (int f = 0; f < 16; ++f)
            wb[f] = *(const bf16x8*)&wt[f * 512];

        float4 n0a, n0b, n1a, n1b;
        if (t + 1 < 16) {                // prefetch next x chunk
            const float* xn = xp + (t + 1) * 64;
            n0a = ntload4(xn);
            n0b = ntload4(xn + 4);
            n1a = ntload4(xn + 32);
            n1b = ntload4(xn + 36);
        }

        bf16x8 ah0, al0, ah1, al1;       // convert current x chunk (VALU,
        cvt8(c0a, c0b, ah0, al0);        //  overlaps the W-load latency)
        cvt8(c1a, c1b, ah1, al1);

        #pragma unroll
        for (int ks = 0; ks < 2; ++ks) {
            const bf16x8 a_h = ks ? ah1 : ah0;
            const bf16x8 a_l = ks ? al1 : al0;
            #pragma unroll
            for (int nt = 0; nt < 4; ++nt) {
                const bf16x8 w_h = wb[(ks * 4 + nt) * 2 + 0];
                const bf16x8 w_l = wb[(ks * 4 + nt) * 2 + 1];
                acc[nt] = __builtin_amdgcn_mfma_f32_16x16x32_bf16(a_h, w_h, acc[nt], 0, 0, 0);
                acc[nt] = __builtin_amdgcn_mfma_f32_16x16x32_bf16(a_h, w_l, acc[nt], 0, 0, 0);
                acc[nt] = __builtin_amdgcn_mfma_f32_16x16x32_bf16(a_l, w_h, acc[nt], 0, 0, 0);
            }
        }
        c0a = n0a; c0b = n0b; c1a = n1a; c1b = n1b;
    }

    // ---- merge K-quarters (D layout: col=fr, row=q*4+r) ----
    #pragma unroll
    for (int nt = 0; nt < 4; ++nt)
        #pragma unroll
        for (int r = 0; r < 4; ++r)
            patch[w][q * 4 + r][nt * 16 + fr] = acc[nt][r];
    __syncthreads();

    // ---- epilogue: 4 waves x 4 rows ----
    float impacc = 0.f, loadacc = 0.f;
    #pragma unroll
    for (int rr = 0; rr < 4; ++rr) {
        const int row  = w * 4 + rr;
        const int grow = rg * 16 + row;
        float v = patch[0][row][lane] + patch[1][row][lane]
                + patch[2][row][lane] + patch[3][row][lane]
                + noise[(size_t)grow * NEXP + lane];

        float m = v;
        #pragma unroll
        for (int off = 32; off; off >>= 1) m = fmaxf(m, __shfl_xor(m, off));
        const float ex = __expf(v - m);
        float s = ex;
        #pragma unroll
        for (int off = 32; off; off >>= 1) s += __shfl_xor(s, off);
        const float g = ex * (1.0f / s);
        impacc += g;

        float work = v, vprev = 0.f;
        float myv = 0.f, sumtop = 0.f;
        int myi = 0, mine = 0, flg = 0;
        #pragma unroll
        for (int j = 0; j < 9; ++j) {
            float bv = work, bg = g; int bi = lane;
            #pragma unroll
            for (int off = 32; off; off >>= 1) {
                const float ov = __shfl_xor(bv, off);
                const int   oi = __shfl_xor(bi, off);
                const float og = __shfl_xor(bg, off);
                if (ov > bv || (ov == bv && oi < bi)) { bv = ov; bi = oi; bg = og; }
            }
            if (j > 0) flg |= (vprev - bv < TAU) ? 1 : 0;
            vprev = bv;
            if (j < 8) {
                sumtop += bg;
                if (lane == j)  { myv = bg; myi = bi; }
                if (lane == bi) { work = -3e38f; mine = 1; }
            }
        }
        loadacc += (float)mine;

        if (lane < 8) {
            out_gates[(size_t)grow * 8 + lane] = myv / sumtop;
            out_idx  [(size_t)grow * 8 + lane] = (float)myi;
        }
        if (lane == 0 && flg) {
            const int pos = atomicAdd(counter, 1);
            worklist[pos] = grow;
        }
    }

    red[w][lane] = impacc;
    __syncthreads();
    if (w == 0)
        ws_imp[(size_t)rg * NEXP + lane] =
            red[0][lane] + red[1][lane] + red[2][lane] + red[3][lane];
    __syncthreads();
    red[w][lane] = loadacc;
    __syncthreads();
    if (w == 0)
        ws_load[(size_t)rg * NEXP + lane] =
            red[0][lane] + red[1][lane] + red[2][lane] + red[3][lane];
}

// ---------------- Kernel B: stage-1 loss reduction (1024 -> 64) ----------------
__global__ __launch_bounds__(256) void reduce_stage(
    const float* __restrict__ ws_imp, const float* __restrict__ ws_load,
    float* __restrict__ st_imp, float* __restrict__ st_load)
{
    __shared__ float si[4][NEXP], sl[4][NEXP];
    const int tid = threadIdx.x, e = tid & 63, sub = tid >> 6;
    float a = 0.f, b = 0.f;
    #pragma unroll
    for (int i = 0; i < 4; ++i) {
        const int blk = (int)blockIdx.x * 16 + sub * 4 + i;
        a += ws_imp[(size_t)blk * NEXP + e];
        b += ws_load[(size_t)blk * NEXP + e];
    }
    si[sub][e] = a; sl[sub][e] = b;
    __syncthreads();
    if (sub == 0) {
        st_imp [(size_t)blockIdx.x * NEXP + e] = si[0][e] + si[1][e] + si[2][e] + si[3][e];
        st_load[(size_t)blockIdx.x * NEXP + e] = sl[0][e] + sl[1][e] + sl[2][e] + sl[3][e];
    }
}

// ---------------- Kernel C: fp64 repair (worklist) + loss finalize ----------------
__global__ __launch_bounds__(256) void repair_finalize(
    const float* __restrict__ x, const float* __restrict__ Wg,
    const float* __restrict__ noise, const int* __restrict__ worklist,
    const int* __restrict__ counter, const float* __restrict__ st_imp,
    const float* __restrict__ st_load, float* __restrict__ out_gates,
    float* __restrict__ out_idx, float* __restrict__ loss_out)
{
    const int tid = threadIdx.x, lane = tid & 63, w = tid >> 6;

    if (blockIdx.x == RB) {                     // ---- loss finalize ----
        __shared__ float si[4][NEXP], sl[4][NEXP];
        float a = 0.f, b = 0.f;
        #pragma unroll
        for (int j = 0; j < RBLK / 4; ++j) {
            const int blk = w * (RBLK / 4) + j;
            a += st_imp[(size_t)blk * NEXP + lane];
            b += st_load[(size_t)blk * NEXP + lane];
        }
        si[w][lane] = a; sl[w][lane] = b;
        __syncthreads();
        if (w == 0) {
            const float imp = (si[0][lane] + si[1][lane] + si[2][lane] + si[3][lane])
                              / (float)NROWS;
            const float ld  = (sl[0][lane] + sl[1][lane] + sl[2][lane] + sl[3][lane])
                              / (float)(NROWS * 8);
            float term = imp * ld;
            #pragma unroll
            for (int off = 32; off; off >>= 1) term += __shfl_xor(term, off);
            if (lane == 0) *loss_out = term * (float)NEXP;
        }
        return;
    }

    // ---- repair: ~1 flagged row per block; 8 fp64 chains ----
    __shared__ float xr[DDIM];
    __shared__ double red64[4][NEXP];
    const int count = *counter;

    for (int i = (int)blockIdx.x; i < count; i += RB) {
        const int grow = worklist[i];
        __syncthreads();
        #pragma unroll
        for (int qq = 0; qq < 4; ++qq)
            ((float4*)xr)[tid + 256 * qq] =
                ((const float4*)(x + (size_t)grow * DDIM))[tid + 256 * qq];
        __syncthreads();

        double ch[8];
        #pragma unroll
        for (int c = 0; c < 8; ++c) ch[c] = 0.0;
        const float* wp = Wg + (size_t)(w * 1024) * NEXP + lane;
        const float* xq = xr + w * 1024;
        #pragma unroll 4
        for (int k = 0; k < 1024; k += 8) {
            #pragma unroll
            for (int c = 0; c < 8; ++c)
                ch[c] = fma((double)xq[k + c],
                            (double)wp[(size_t)(k + c) * NEXP], ch[c]);
        }
        red64[w][lane] = (((ch[0] + ch[1]) + (ch[2] + ch[3]))
                        + ((ch[4] + ch[5]) + (ch[6] + ch[7])));
        __syncthreads();

        if (w == 0) {
            const double v64 = (((red64[0][lane] + red64[1][lane]) + red64[2][lane])
                                + red64[3][lane]) + (double)noise[(size_t)grow * NEXP + lane];
            double m = v64;
            #pragma unroll
            for (int off = 32; off; off >>= 1) m = fmax(m, __shfl_xor(m, off));
            const float ex = __expf((float)(v64 - m));
            float s = ex;
            #pragma unroll
            for (int off = 32; off; off >>= 1) s += __shfl_xor(s, off);
            const float g = ex * (1.0f / s);

            double work = v64;
            float myv = 0.f, sumtop = 0.f, bg;
            int myi = 0;
            #pragma unroll
            for (int j = 0; j < 8; ++j) {
                double bv = work; int bi = lane; bg = g;
                #pragma unroll
                for (int off = 32; off; off >>= 1) {
                    const double ov = __shfl_xor(bv, off);
                    const int    oi = __shfl_xor(bi, off);
                    const float  og = __shfl_xor(bg, off);
                    if (ov > bv || (ov == bv && oi < bi)) { bv = ov; bi = oi; bg = og; }
                }
                sumtop += bg;
                if (lane == j)  { myv = bg; myi = bi; }
                if (lane == bi) work = -1e300;
            }
            if (lane < 8) {
                out_gates[(size_t)grow * 8 + lane] = myv / sumtop;
                out_idx  [(size_t)grow * 8 + lane] = (float)myi;
            }
        }
    }
}

extern "C" void kernel_launch(void* const* d_in, const int* in_sizes, int n_in,
                              void* d_out, int out_size, void* d_ws, size_t ws_size,
                              hipStream_t stream) {
    const float* x     = (const float*)d_in[0];
    const float* Wg    = (const float*)d_in[1];
    const float* noise = (const float*)d_in[2];
    float* out       = (float*)d_out;
    float* out_gates = out;
    float* out_idx   = out + (size_t)NROWS * 8;
    float* loss_out  = out + (size_t)2 * NROWS * 8;

    // ws: wfrag[1Mi ushort] | ws_imp[FB*64] | ws_load | st_imp[64*64] | st_load | worklist | counter
    ushort* wfrag  = (ushort*)d_ws;
    float* ws_imp   = (float*)(wfrag + (size_t)1048576);
    float* ws_load  = ws_imp + (size_t)FB * NEXP;
    float* st_imp   = ws_load + (size_t)FB * NEXP;
    float* st_load  = st_imp + (size_t)RBLK * NEXP;
    int*   worklist = (int*)(st_load + (size_t)RBLK * NEXP);
    int*   counter  = worklist + NROWS;

    hipMemsetAsync(counter, 0, sizeof(int), stream);
    wprep          <<<128,    256, 0, stream>>>(Wg, wfrag);
    router_fused   <<<FB,     256, 0, stream>>>(x, wfrag, noise, out_gates, out_idx,
                                                ws_imp, ws_load, worklist, counter);
    reduce_stage   <<<RBLK,   256, 0, stream>>>(ws_imp, ws_load, st_imp, st_load);
    repair_finalize<<<RB + 1, 256, 0, stream>>>(x, Wg, noise, worklist, counter,
                                                st_imp, st_load, out_gates, out_idx,
                                                loss_out);
}

// Round 13
// 144.796 us; speedup vs baseline: 1.3183x; 1.3183x over previous
//
#include <hip/hip_runtime.h>

#define NROWS 16384
#define DDIM  4096
#define NEXP  64
#define TAU   1e-3f
#define CB    2048        // combine blocks (8 rows each)
#define RB    2048        // repair worker blocks
#define RBLK  64          // reduce_stage output blocks

typedef __attribute__((ext_vector_type(8))) short bf16x8;
typedef __attribute__((ext_vector_type(4))) float f32x4;

__device__ __forceinline__ ushort f2bf(float f) {   // fp32 -> bf16 RN-even
    uint u = __float_as_uint(f);
    u += 0x7FFFu + ((u >> 16) & 1u);
    return (ushort)(u >> 16);
}
__device__ __forceinline__ float bf2f(ushort h) {
    return __uint_as_float(((uint)h) << 16);
}
__device__ __forceinline__ void cvt8(const float4& a, const float4& b,
                                     bf16x8& H, bf16x8& L) {
    const float v[8] = {a.x, a.y, a.z, a.w, b.x, b.y, b.z, b.w};
    #pragma unroll
    for (int i = 0; i < 8; ++i) {
        const ushort h = f2bf(v[i]);
        H[i] = (short)h;
        L[i] = (short)f2bf(v[i] - bf2f(h));
    }
}

// ---------------- Kernel P: W -> fragment-major bf16 hi/lo (once, 2 MB) ----
// Chunk c (64 k) = wfrag[c*8192 ..). Fragment f=(ks*4+nt)*2+prod at
// [f*512 + lane*8]: W[c*64+ks*32+8*(lane>>4)+j][nt*16+(lane&15)].
// (Layout verified by R8-R12 passing refcheck.)
__global__ __launch_bounds__(256) void wprep(
    const float* __restrict__ Wg, ushort* __restrict__ wfrag)
{
    const int gid  = (int)blockIdx.x * 256 + threadIdx.x;   // 0..32767
    const int lane = gid & 63, frag = gid >> 6;             // frag 0..511
    const int nt = frag & 3, ks = (frag >> 2) & 1, tg = frag >> 3;
    const int k0 = tg * 64 + ks * 32 + (lane >> 4) * 8;
    const int e  = nt * 16 + (lane & 15);
    bf16x8 H, L;
    #pragma unroll
    for (int j = 0; j < 8; ++j) {
        const float v = Wg[(size_t)(k0 + j) * NEXP + e];
        const ushort h = f2bf(v);
        H[j] = (short)h;
        L[j] = (short)f2bf(v - bf2f(h));
    }
    *(bf16x8*)&wfrag[((size_t)frag * 2 + 0) * 512 + lane * 8] = H;
    *(bf16x8*)&wfrag[((size_t)frag * 2 + 1) * 512 + lane * 8] = L;
}

// ---------------- Kernel A: MFMA GEMM, LDS-shared W, partials out ----------
// 512 blocks x 256 thr (4 waves): rb=blockIdx>>1 (64 rows), kq=blockIdx&1
// (K-half, 32 chunks of 64k). Wave w owns rows rb*64+w*16..+15, all 64
// experts. Per chunk: W (preconverted wfrag, 16 KB) is staged into LDS ONCE
// per block and shared by the 4 waves (kills R11's per-wave 1 GB L2/L3
// re-read). T14: W+x loads for t+1 issued at chunk top; compute from
// buf[cur]; ds_write W late into buf^1; one barrier/chunk. 2 blocks/CU.
__global__ __launch_bounds__(256, 2) void gemm_mfma(
    const float* __restrict__ x, const ushort* __restrict__ wfrag,
    float* __restrict__ partials, int* __restrict__ counter)
{
    if (blockIdx.x == 0 && threadIdx.x == 0) *counter = 0;

    __shared__ ushort wbuf[2][8192];     // double-buffered W chunk, 32 KB

    const int tid  = threadIdx.x;
    const int lane = tid & 63;
    const int w    = tid >> 6;
    const int rb   = (int)blockIdx.x >> 1;
    const int kq   = (int)blockIdx.x & 1;
    const int fr   = lane & 15;
    const int q    = lane >> 4;

    const float*  xp   = x + (size_t)(rb * 64 + w * 16 + fr) * DDIM
                           + kq * 2048 + q * 8;
    const ushort* wsrc = wfrag + (size_t)(kq * 32) * 8192 + tid * 8;

    f32x4 acc[4];
    #pragma unroll
    for (int nt = 0; nt < 4; ++nt) acc[nt] = (f32x4){0.f, 0.f, 0.f, 0.f};

    // prologue: stage chunk 0 -> buf0, issue x(0)
    uint4 wst[4];
    #pragma unroll
    for (int c = 0; c < 4; ++c)
        wst[c] = *(const uint4*)(wsrc + c * 2048);
    #pragma unroll
    for (int c = 0; c < 4; ++c)
        *(uint4*)&wbuf[0][c * 2048 + tid * 8] = wst[c];
    float4 c0a = *(const float4*)(xp);
    float4 c0b = *(const float4*)(xp + 4);
    float4 c1a = *(const float4*)(xp + 32);
    float4 c1b = *(const float4*)(xp + 36);
    __syncthreads();

    int cur = 0;
    for (int t = 0; t < 32; ++t) {
        float4 n0a, n0b, n1a, n1b;
        if (t + 1 < 32) {               // ISSUE t+1 loads at chunk TOP (T14)
            #pragma unroll
            for (int c = 0; c < 4; ++c)
                wst[c] = *(const uint4*)(wsrc + (size_t)(t + 1) * 8192 + c * 2048);
            const float* xn = xp + (t + 1) * 64;
            n0a = *(const float4*)(xn);
            n0b = *(const float4*)(xn + 4);
            n1a = *(const float4*)(xn + 32);
            n1b = *(const float4*)(xn + 36);
        }

        bf16x8 ah0, al0, ah1, al1;      // convert current x (overlaps loads)
        cvt8(c0a, c0b, ah0, al0);
        cvt8(c1a, c1b, ah1, al1);

        const ushort* wt = &wbuf[cur][0];
        #pragma unroll
        for (int ks = 0; ks < 2; ++ks) {
            const bf16x8 a_h = ks ? ah1 : ah0;
            const bf16x8 a_l = ks ? al1 : al0;
            #pragma unroll
            for (int nt = 0; nt < 4; ++nt) {
                const bf16x8 w_h =
                    *(const bf16x8*)&wt[((ks * 4 + nt) * 2 + 0) * 512 + lane * 8];
                const bf16x8 w_l =
                    *(const bf16x8*)&wt[((ks * 4 + nt) * 2 + 1) * 512 + lane * 8];
                acc[nt] = __builtin_amdgcn_mfma_f32_16x16x32_bf16(a_h, w_h, acc[nt], 0, 0, 0);
                acc[nt] = __builtin_amdgcn_mfma_f32_16x16x32_bf16(a_h, w_l, acc[nt], 0, 0, 0);
                acc[nt] = __builtin_amdgcn_mfma_f32_16x16x32_bf16(a_l, w_h, acc[nt], 0, 0, 0);
            }
        }

        if (t + 1 < 32) {               // WRITE staged W late -> idle buffer
            #pragma unroll
            for (int c = 0; c < 4; ++c)
                *(uint4*)&wbuf[cur ^ 1][c * 2048 + tid * 8] = wst[c];
            c0a = n0a; c0b = n0b; c1a = n1a; c1b = n1b;
        }
        __syncthreads();                // one barrier per chunk
        cur ^= 1;
    }

    // partials[kq][grow][e]  (D layout: col=fr, row=q*4+r)
    float* po = partials + ((size_t)kq * NROWS + rb * 64 + w * 16) * 64;
    #pragma unroll
    for (int nt = 0; nt < 4; ++nt)
        #pragma unroll
        for (int r = 0; r < 4; ++r)
            po[(q * 4 + r) * 64 + nt * 16 + fr] = acc[nt][r];
}

// ---------------- Kernel B: combine + softmax + top-9 + worklist ----------------
// CB=2048 blocks, 8 rows/block (2 per wave) — R5-R7 proven structure.
__global__ __launch_bounds__(256) void combine_epilogue(
    const float* __restrict__ partials, const float* __restrict__ noise,
    float* __restrict__ out_gates, float* __restrict__ out_idx,
    float* __restrict__ ws_imp, float* __restrict__ ws_load,
    int* __restrict__ worklist, int* __restrict__ counter)
{
    __shared__ float red[4][NEXP];
    const int tid = threadIdx.x, lane = tid & 63, w = tid >> 6;

    float impacc = 0.f, loadacc = 0.f;
    #pragma unroll
    for (int rr = 0; rr < 2; ++rr) {
        const int grow = (int)blockIdx.x * 8 + w * 2 + rr;
        float v = noise[(size_t)grow * NEXP + lane]
                + partials[(size_t)grow * 64 + lane]
                + partials[(size_t)NROWS * 64 + (size_t)grow * 64 + lane];

        float m = v;
        #pragma unroll
        for (int off = 32; off; off >>= 1) m = fmaxf(m, __shfl_xor(m, off));
        const float ex = __expf(v - m);
        float s = ex;
        #pragma unroll
        for (int off = 32; off; off >>= 1) s += __shfl_xor(s, off);
        const float g = ex * (1.0f / s);
        impacc += g;

        float work = v, vprev = 0.f;
        float myv = 0.f, sumtop = 0.f;
        int myi = 0, mine = 0, flg = 0;
        #pragma unroll
        for (int j = 0; j < 9; ++j) {
            float bv = work, bg = g; int bi = lane;
            #pragma unroll
            for (int off = 32; off; off >>= 1) {
                const float ov = __shfl_xor(bv, off);
                const int   oi = __shfl_xor(bi, off);
                const float og = __shfl_xor(bg, off);
                if (ov > bv || (ov == bv && oi < bi)) { bv = ov; bi = oi; bg = og; }
            }
            if (j > 0) flg |= (vprev - bv < TAU) ? 1 : 0;
            vprev = bv;
            if (j < 8) {
                sumtop += bg;
                if (lane == j)  { myv = bg; myi = bi; }
                if (lane == bi) { work = -3e38f; mine = 1; }
            }
        }
        loadacc += (float)mine;

        if (lane < 8) {
            out_gates[(size_t)grow * 8 + lane] = myv / sumtop;
            out_idx  [(size_t)grow * 8 + lane] = (float)myi;
        }
        if (lane == 0 && flg) {
            const int pos = atomicAdd(counter, 1);
            worklist[pos] = grow;
        }
    }

    red[w][lane] = impacc;
    __syncthreads();
    if (w == 0)
        ws_imp[(size_t)blockIdx.x * NEXP + lane] =
            red[0][lane] + red[1][lane] + red[2][lane] + red[3][lane];
    __syncthreads();
    red[w][lane] = loadacc;
    __syncthreads();
    if (w == 0)
        ws_load[(size_t)blockIdx.x * NEXP + lane] =
            red[0][lane] + red[1][lane] + red[2][lane] + red[3][lane];
}

// ---------------- Kernel B2: stage-1 loss reduction (2048 -> 64) ----------------
__global__ __launch_bounds__(256) void reduce_stage(
    const float* __restrict__ ws_imp, const float* __restrict__ ws_load,
    float* __restrict__ st_imp, float* __restrict__ st_load)
{
    __shared__ float si[4][NEXP], sl[4][NEXP];
    const int tid = threadIdx.x, e = tid & 63, sub = tid >> 6;
    float a = 0.f, b = 0.f;
    #pragma unroll
    for (int i = 0; i < 8; ++i) {
        const int blk = (int)blockIdx.x * 32 + sub * 8 + i;
        a += ws_imp[(size_t)blk * NEXP + e];
        b += ws_load[(size_t)blk * NEXP + e];
    }
    si[sub][e] = a; sl[sub][e] = b;
    __syncthreads();
    if (sub == 0) {
        st_imp [(size_t)blockIdx.x * NEXP + e] = si[0][e] + si[1][e] + si[2][e] + si[3][e];
        st_load[(size_t)blockIdx.x * NEXP + e] = sl[0][e] + sl[1][e] + sl[2][e] + sl[3][e];
    }
}

// ---------------- Kernel C: fp64 repair (worklist) + loss finalize ----------------
__global__ __launch_bounds__(256) void repair_finalize(
    const float* __restrict__ x, const float* __restrict__ Wg,
    const float* __restrict__ noise, const int* __restrict__ worklist,
    const int* __restrict__ counter, const float* __restrict__ st_imp,
    const float* __restrict__ st_load, float* __restrict__ out_gates,
    float* __restrict__ out_idx, float* __restrict__ loss_out)
{
    const int tid = threadIdx.x, lane = tid & 63, w = tid >> 6;

    if (blockIdx.x == RB) {                     // ---- loss finalize ----
        __shared__ float si[4][NEXP], sl[4][NEXP];
        float a = 0.f, b = 0.f;
        #pragma unroll
        for (int j = 0; j < RBLK / 4; ++j) {
            const int blk = w * (RBLK / 4) + j;
            a += st_imp[(size_t)blk * NEXP + lane];
            b += st_load[(size_t)blk * NEXP + lane];
        }
        si[w][lane] = a; sl[w][lane] = b;
        __syncthreads();
        if (w == 0) {
            const float imp = (si[0][lane] + si[1][lane] + si[2][lane] + si[3][lane])
                              / (float)NROWS;
            const float ld  = (sl[0][lane] + sl[1][lane] + sl[2][lane] + sl[3][lane])
                              / (float)(NROWS * 8);
            float term = imp * ld;
            #pragma unroll
            for (int off = 32; off; off >>= 1) term += __shfl_xor(term, off);
            if (lane == 0) *loss_out = term * (float)NEXP;
        }
        return;
    }

    // ---- repair: ~1 flagged row per block; 8 fp64 chains ----
    __shared__ float xr[DDIM];
    __shared__ double red64[4][NEXP];
    const int count = *counter;

    for (int i = (int)blockIdx.x; i < count; i += RB) {
        const int grow = worklist[i];
        __syncthreads();
        #pragma unroll
        for (int qq = 0; qq < 4; ++qq)
            ((float4*)xr)[tid + 256 * qq] =
                ((const float4*)(x + (size_t)grow * DDIM))[tid + 256 * qq];
        __syncthreads();

        double ch[8];
        #pragma unroll
        for (int c = 0; c < 8; ++c) ch[c] = 0.0;
        const float* wp = Wg + (size_t)(w * 1024) * NEXP + lane;
        const float* xq = xr + w * 1024;
        #pragma unroll 4
        for (int k = 0; k < 1024; k += 8) {
            #pragma unroll
            for (int c = 0; c < 8; ++c)
                ch[c] = fma((double)xq[k + c],
                            (double)wp[(size_t)(k + c) * NEXP], ch[c]);
        }
        red64[w][lane] = (((ch[0] + ch[1]) + (ch[2] + ch[3]))
                        + ((ch[4] + ch[5]) + (ch[6] + ch[7])));
        __syncthreads();

        if (w == 0) {
            const double v64 = (((red64[0][lane] + red64[1][lane]) + red64[2][lane])
                                + red64[3][lane]) + (double)noise[(size_t)grow * NEXP + lane];
            double m = v64;
            #pragma unroll
            for (int off = 32; off; off >>= 1) m = fmax(m, __shfl_xor(m, off));
            const float ex = __expf((float)(v64 - m));
            float s = ex;
            #pragma unroll
            for (int off = 32; off; off >>= 1) s += __shfl_xor(s, off);
            const float g = ex * (1.0f / s);

            double work = v64;
            float myv = 0.f, sumtop = 0.f, bg;
            int myi = 0;
            #pragma unroll
            for (int j = 0; j < 8; ++j) {
                double bv = work; int bi = lane; bg = g;
                #pragma unroll
                for (int off = 32; off; off >>= 1) {
                    const double ov = __shfl_xor(bv, off);
                    const int    oi = __shfl_xor(bi, off);
                    const float  og = __shfl_xor(bg, off);
                    if (ov > bv || (ov == bv && oi < bi)) { bv = ov; bi = oi; bg = og; }
                }
                sumtop += bg;
                if (lane == j)  { myv = bg; myi = bi; }
                if (lane == bi) work = -1e300;
            }
            if (lane < 8) {
                out_gates[(size_t)grow * 8 + lane] = myv / sumtop;
                out_idx  [(size_t)grow * 8 + lane] = (float)myi;
            }
        }
    }
}

extern "C" void kernel_launch(void* const* d_in, const int* in_sizes, int n_in,
                              void* d_out, int out_size, void* d_ws, size_t ws_size,
                              hipStream_t stream) {
    const float* x     = (const float*)d_in[0];
    const float* Wg    = (const float*)d_in[1];
    const float* noise = (const float*)d_in[2];
    float* out       = (float*)d_out;
    float* out_gates = out;
    float* out_idx   = out + (size_t)NROWS * 8;
    float* loss_out  = out + (size_t)2 * NROWS * 8;

    // ws: wfrag[1Mi ushort] | partials[2*16384*64] | ws_imp[CB*64] | ws_load
    //     | st_imp[64*64] | st_load | worklist[16384] | counter
    ushort* wfrag   = (ushort*)d_ws;
    float* partials = (float*)(wfrag + (size_t)1048576);
    float* ws_imp   = partials + (size_t)2 * NROWS * 64;
    float* ws_load  = ws_imp + (size_t)CB * NEXP;
    float* st_imp   = ws_load + (size_t)CB * NEXP;
    float* st_load  = st_imp + (size_t)RBLK * NEXP;
    int*   worklist = (int*)(st_load + (size_t)RBLK * NEXP);
    int*   counter  = worklist + NROWS;

    wprep          <<<128,    256, 0, stream>>>(Wg, wfrag);
    gemm_mfma      <<<512,    256, 0, stream>>>(x, wfrag, partials, counter);
    combine_epilogue<<<CB,    256, 0, stream>>>(partials, noise, out_gates, out_idx,
                                                ws_imp, ws_load, worklist, counter);
    reduce_stage   <<<RBLK,   256, 0, stream>>>(ws_imp, ws_load, st_imp, st_load);
    repair_finalize<<<RB + 1, 256, 0, stream>>>(x, Wg, noise, worklist, counter,
                                                st_imp, st_load, out_gates, out_idx,
                                                loss_out);
}